// Round 17
// baseline (7727.858 us; speedup 1.0000x reference)
//
#include <hip/hip_runtime.h>
#include <math.h>

#define N_  2048
#define T_  200
#define D_  16
#define H_  64
#define C2_ 128
#define BM  8
#define NTHR 1024
#define NBLK 256

// X slot: [128][2048] bf16 + 4KB guard gap
#define SLOT_USH ((size_t)C2_ * N_ + 2048)

typedef unsigned short ushort_t;
typedef short bf16x8 __attribute__((ext_vector_type(8)));
typedef float f32x4 __attribute__((ext_vector_type(4)));

// ---- weight blob layout (ushort offsets) ----
#define W_HC 0        // W_h_cur^T  [64][64]  swz8
#define W_HP 4096     // W_h_prev^T [64][64]  swz8
#define W_CC 8192     // W_c_cur^T  [64][64]  swz8
#define W_CP 12288    // W_c_prev^T [64][64]  swz8
#define W_G  16384    // [Wgh^T ; Wgc^T] [128][64] swz8
#define W_R  24576    // R^T [256][64] swz8
#define W_K  40960    // K^T [256][16] swz2  (read from GLOBAL in epiC)
#define W_USH 45056   // then 512 fp32 biases
#define BLOB_BYTES 92160

__device__ __forceinline__ float sig_(float x) {
    return __fdividef(1.0f, 1.0f + __expf(-x));
}
__device__ __forceinline__ float tanh_(float x) {
    float e = __expf(-2.0f * fabsf(x));
    float t = __fdividef(1.0f - e, 1.0f + e);
    return copysignf(t, x);
}
__device__ __forceinline__ ushort_t f2bf(float f) {
    unsigned u = __float_as_uint(f);
    u = (u + 0x7FFFu + ((u >> 16) & 1u)) >> 16;
    return (ushort_t)u;
}
__device__ __forceinline__ float blo(unsigned u){ return __uint_as_float(u << 16); }
__device__ __forceinline__ float bhi(unsigned u){ return __uint_as_float(u & 0xFFFF0000u); }

__device__ __forceinline__ void gload16(const void* g, void* l) {
    __builtin_amdgcn_global_load_lds(
        (const __attribute__((address_space(1))) unsigned int*)g,
        (__attribute__((address_space(3))) unsigned int*)l, 16, 0, 0);
}

// B-fragment load (DEEP: fresh-slot cached; else uncached agent-scope)
template<bool DEEP>
__device__ __forceinline__ bf16x8 ldB(const ushort_t* p) {
    if constexpr (DEEP) {
        return *(const bf16x8*)p;
    } else {
        union { unsigned long long q[2]; bf16x8 v; } u;
        u.q[0] = __hip_atomic_load((const unsigned long long*)p,
                                   __ATOMIC_RELAXED, __HIP_MEMORY_SCOPE_AGENT);
        u.q[1] = __hip_atomic_load(((const unsigned long long*)p) + 1,
                                   __ATOMIC_RELAXED, __HIP_MEMORY_SCOPE_AGENT);
        return u.v;
    }
}

// ---- A (fp32) -> A (bf16); zero all barrier counters (1024 slots) ----
__global__ __launch_bounds__(256) void convert_A_kernel(
    const float* __restrict__ A, ushort_t* __restrict__ Abf,
    unsigned* __restrict__ cnt)
{
    if (blockIdx.x == 0) {
        #pragma unroll
        for (int p = 0; p < 4; p++)
            __hip_atomic_store(cnt + p * 256 + threadIdx.x, 0u,
                               __ATOMIC_RELAXED, __HIP_MEMORY_SCOPE_AGENT);
    }
    size_t i = ((size_t)blockIdx.x * 256 + threadIdx.x) * 4;
    float4 v = *(const float4*)(A + i);
    ushort4 o;
    o.x = f2bf(v.x); o.y = f2bf(v.y); o.z = f2bf(v.z); o.w = f2bf(v.w);
    *(ushort4*)(Abf + i) = o;
}

// ---- pack weights: bf16, transposed, XOR-swizzled 16B chunks ----
__global__ __launch_bounds__(256) void convert_W_kernel(
    const float* __restrict__ Whc, const float* __restrict__ Whp,
    const float* __restrict__ Wcc, const float* __restrict__ Wcp,
    const float* __restrict__ Wgh, const float* __restrict__ Wgc,
    const float* __restrict__ R,   const float* __restrict__ Kw,
    const float* __restrict__ bh,  const float* __restrict__ bc,
    const float* __restrict__ bgh, const float* __restrict__ bgc,
    const float* __restrict__ bl,
    ushort_t* __restrict__ blob)
{
    const int stride = gridDim.x * 256;
    const int gid = blockIdx.x * 256 + threadIdx.x;
    for (int idx = gid; idx < 4096; idx += stride) {
        int k = idx >> 6, c = idx & 63;
        int dst = c * 64 + ((((k >> 3) ^ c) & 7) << 3) + (k & 7);
        blob[W_HC + dst] = f2bf(Whc[idx]);
        blob[W_HP + dst] = f2bf(Whp[idx]);
        blob[W_CC + dst] = f2bf(Wcc[idx]);
        blob[W_CP + dst] = f2bf(Wcp[idx]);
        blob[W_G + dst]        = f2bf(Wgh[idx]);
        blob[W_G + 4096 + dst] = f2bf(Wgc[idx]);
    }
    for (int idx = gid; idx < 16384; idx += stride) {
        int k = idx >> 8, gc = idx & 255;
        int dst = gc * 64 + ((((k >> 3) ^ gc) & 7) << 3) + (k & 7);
        blob[W_R + dst] = f2bf(R[idx]);
    }
    for (int idx = gid; idx < 4096; idx += stride) {
        int d = idx >> 8, gc = idx & 255;
        int dst = gc * 16 + ((((d >> 3) ^ gc) & 1) << 3) + (d & 7);
        blob[W_K + dst] = f2bf(Kw[idx]);
    }
    float* bf = (float*)(blob + W_USH);
    if (gid < 64) { bf[gid] = bh[gid]; bf[64+gid] = bc[gid]; bf[128+gid] = bgh[gid]; bf[192+gid] = bgc[gid]; }
    if (gid < 256) bf[256 + gid] = bl[gid];
}

// ---- Prologue: X_0^T (premultiplied, bf16, slot 0), h_lstm_0, c_lstm_0 ----
__global__ __launch_bounds__(64) void prologue_kernel(
    const float* __restrict__ xin, const float* __restrict__ h0,
    const float* __restrict__ c0,
    const float* __restrict__ Wgh, const float* __restrict__ bgh,
    const float* __restrict__ Wgc, const float* __restrict__ bgc,
    const float* __restrict__ K, const float* __restrict__ R,
    const float* __restrict__ bl,
    ushort_t* __restrict__ Xt, float* __restrict__ hl, float* __restrict__ cl)
{
    const int n = blockIdx.x;
    const int j = threadIdx.x;
    __shared__ float hs[H_], cs[H_], xs[D_];
    hs[j] = h0[n * H_ + j];
    cs[j] = c0[n * H_ + j];
    if (j < D_) xs[j] = xin[(size_t)n * T_ * D_ + j];
    __syncthreads();

    float xh = bgh[j], xc = bgc[j];
    for (int k = 0; k < H_; k++) {
        xh += hs[k] * Wgh[k * H_ + j];
        xc += cs[k] * Wgc[k * H_ + j];
    }
    Xt[(size_t)j * N_ + n]        = f2bf(xh);
    Xt[(size_t)(H_ + j) * N_ + n] = f2bf(xc);

    float zi = bl[j], zf = bl[H_ + j], zg = bl[2 * H_ + j], zo = bl[3 * H_ + j];
    for (int d = 0; d < D_; d++) {
        float xv = xs[d];
        zi += xv * K[d * 256 + j];
        zf += xv * K[d * 256 + 64 + j];
        zg += xv * K[d * 256 + 128 + j];
        zo += xv * K[d * 256 + 192 + j];
    }
    for (int k = 0; k < H_; k++) {
        float hv = hs[k];
        zi += hv * R[k * 256 + j];
        zf += hv * R[k * 256 + 64 + j];
        zg += hv * R[k * 256 + 128 + j];
        zo += hv * R[k * 256 + 192 + j];
    }
    float clv = sig_(zf) * cs[j] + sig_(zi) * tanh_(zg);
    float hlv = sig_(zo) * tanh_(clv);
    cl[n * H_ + j] = clv;
    hl[n * H_ + j] = hlv;
}

// ---- Persistent kernel (R15 + sched_barrier fence in GEMM bursts) ----
template<bool DEEP>
__global__ __launch_bounds__(NTHR, 4) void persistent_kernel(
    const ushort_t* __restrict__ Abf,
    ushort_t* __restrict__ Xs,
    const float* __restrict__ hl, const float* __restrict__ clm,
    const float* __restrict__ xin,
    const ushort_t* __restrict__ Wblob,
    float* __restrict__ oh, float* __restrict__ oc,
    unsigned* __restrict__ cnt)
{
    __shared__ __align__(16) ushort_t WL[46080];     // 90 KB weights+biases
    __shared__ __align__(16) ushort_t Alds[BM * N_]; // 32 KB A-panel, chunk-swizzled
    __shared__ __align__(16) float HLs[BM * H_], CLs[BM * H_];
    __shared__ __align__(16) float XSs[BM * D_];
    __shared__ __align__(16) float part[4 * BM * C2_];   // 16 KB; aliased as XBf
    __shared__ __align__(16) float Gs[BM * C2_];
    __shared__ __align__(16) float HNs[BM * H_], CNs[BM * H_];

    const int tid  = threadIdx.x;
    const int brow = blockIdx.x * BM;
    const int wave = tid >> 6;
    const int lane = tid & 63;

    // barrier tree: root = cnt[0]; group g counter = cnt[32 + g*32]
    unsigned* grpc = cnt + 32 + (blockIdx.x >> 4) * 32;
    unsigned* root = cnt;

    // ---- one-time staging: weights + state ----
    {
        const char* gsrc = (const char*)Wblob;
        char* lbase = (char*)WL;
        for (int i = wave; i < 90; i += 16)
            gload16(gsrc + i * 1024 + lane * 16, lbase + i * 1024);
        if (wave == 0) {
            gload16((const char*)(hl + (size_t)brow * H_) + lane * 16, (char*)HLs);
            gload16((const char*)(hl + (size_t)brow * H_) + 1024 + lane * 16, (char*)HLs + 1024);
        }
        if (wave == 1) {
            gload16((const char*)(clm + (size_t)brow * H_) + lane * 16, (char*)CLs);
            gload16((const char*)(clm + (size_t)brow * H_) + 1024 + lane * 16, (char*)CLs + 1024);
        }
    }
    // ---- one-time: A-panel -> LDS, 16B-chunk XOR swizzle ----
    for (int idx = tid; idx < BM * 256; idx += NTHR) {
        int row = idx >> 8;
        int kc  = idx & 255;
        bf16x8 v = *(const bf16x8*)(Abf + (size_t)(brow + row) * N_ + kc * 8);
        int swzc = (kc & ~7) | ((kc ^ row) & 7);
        *(bf16x8*)((char*)Alds + row * 4096 + swzc * 16) = v;
    }
    __syncthreads();

    const float* BL = (const float*)(WL + W_USH);

    for (int t = 0; t < T_; t++) {
        const ushort_t* Xc = Xs + (size_t)(DEEP ? t : (t & 1)) * SLOT_USH;
        ushort_t*       Xn = Xs + (size_t)(DEEP ? (t + 1) : ((t + 1) & 1)) * SLOT_USH;

        // prefetch x_{t+1} (drains at next barrier)
        if (t + 1 < T_ && wave == 7 && lane < 32) {
            const float* g = xin + (size_t)(brow + (lane >> 2)) * (T_ * D_)
                                 + (size_t)(t + 1) * D_ + (lane & 3) * 4;
            gload16(g, (char*)XSs);
        }

        // ---- GEMM: 16 waves = 4 col-tiles x 4 k-quarters (block-rotated);
        //      two-pass burst-16 B-loads, fenced so all 16 stay in flight ----
        {
            const int ct = (wave & 3) * 32;
            const int kq = ((((wave >> 2) + blockIdx.x) & 3)) * 512;  // per-block k-rotation
            const int fr = lane & 15;
            const int kg = lane >> 4;
            const int arow = fr & 7;
            const int kcb = (kq >> 3) + kg;
            const ushort_t* Bp0 = Xc + (size_t)(ct + fr) * N_ + kq + kg * 8;
            const ushort_t* Bp1 = Bp0 + (size_t)16 * N_;
            f32x4 acc0 = {0.f, 0.f, 0.f, 0.f}, acc1 = {0.f, 0.f, 0.f, 0.f};

            bf16x8 rb[16];
            #pragma unroll
            for (int kk = 0; kk < 16; kk++) rb[kk] = ldB<DEEP>(Bp0 + kk * 32);
            __builtin_amdgcn_sched_barrier(0);   // keep all 16 loads in flight
            #pragma unroll
            for (int kk = 0; kk < 16; kk++) {
                const int kc  = kcb + kk * 4;
                const int swzc = (kc & ~7) | ((kc ^ arow) & 7);
                bf16x8 a = *(const bf16x8*)((const char*)Alds + arow * 4096 + swzc * 16);
                acc0 = __builtin_amdgcn_mfma_f32_16x16x32_bf16(a, rb[kk], acc0, 0, 0, 0);
            }
            __builtin_amdgcn_sched_barrier(0);
            #pragma unroll
            for (int kk = 0; kk < 16; kk++) rb[kk] = ldB<DEEP>(Bp1 + kk * 32);
            __builtin_amdgcn_sched_barrier(0);   // keep all 16 loads in flight
            #pragma unroll
            for (int kk = 0; kk < 16; kk++) {
                const int kc  = kcb + kk * 4;
                const int swzc = (kc & ~7) | ((kc ^ arow) & 7);
                bf16x8 a = *(const bf16x8*)((const char*)Alds + arow * 4096 + swzc * 16);
                acc1 = __builtin_amdgcn_mfma_f32_16x16x32_bf16(a, rb[kk], acc1, 0, 0, 0);
            }
            if (kg < 2) {
                float* pp = &part[(wave >> 2) * (BM * C2_) + ct];
                const int rb4 = kg * 4;
                #pragma unroll
                for (int r = 0; r < 4; r++) {
                    pp[(rb4 + r) * C2_ + fr]      = acc0[r];
                    pp[(rb4 + r) * C2_ + 16 + fr] = acc1[r];
                }
            }
        }
        __syncthreads();

        // ---- reduce 4 k-partials + tanh -> Gs ----
        Gs[tid] = tanh_(part[tid] + part[1024 + tid] + part[2048 + tid] + part[3072 + tid]);
        __syncthreads();

        // ---- epilogue A: h_new / c_new + output store ----
        if (tid < 512) {
            const int c = tid & 63;
            const int r = tid >> 6;
            const int swz = c & 7;
            float ah = BL[c], ac = BL[64 + c];
            #pragma unroll
            for (int kk = 0; kk < 8; kk++) {
                const int pc = ((kk ^ swz) << 3);
                uint4 w1 = *(const uint4*)&WL[W_HC + c * 64 + pc];
                uint4 w2 = *(const uint4*)&WL[W_HP + c * 64 + pc];
                uint4 w3 = *(const uint4*)&WL[W_CC + c * 64 + pc];
                uint4 w4 = *(const uint4*)&WL[W_CP + c * 64 + pc];
                const float* hb = &HLs[r * 64 + kk * 8];
                const float* gh = &Gs[r * 128 + kk * 8];
                const float* cb = &CLs[r * 64 + kk * 8];
                const float* gc = &Gs[r * 128 + 64 + kk * 8];
                const unsigned* u1 = (const unsigned*)&w1;
                const unsigned* u2 = (const unsigned*)&w2;
                const unsigned* u3 = (const unsigned*)&w3;
                const unsigned* u4 = (const unsigned*)&w4;
                #pragma unroll
                for (int q = 0; q < 4; q++) {
                    ah += blo(u1[q]) * hb[2*q] + bhi(u1[q]) * hb[2*q+1];
                    ah += blo(u2[q]) * gh[2*q] + bhi(u2[q]) * gh[2*q+1];
                    ac += blo(u3[q]) * cb[2*q] + bhi(u3[q]) * cb[2*q+1];
                    ac += blo(u4[q]) * gc[2*q] + bhi(u4[q]) * gc[2*q+1];
                }
            }
            float hnv = sig_(ah), cnv = sig_(ac);
            HNs[r * 64 + c] = hnv;
            CNs[r * 64 + c] = cnv;
            size_t o = (size_t)(brow + r) * (T_ * H_) + (size_t)t * H_ + c;
            oh[o] = hnv;
            oc[o] = cnv;
        }

        if (t + 1 == T_) break;
        __syncthreads();

        // ---- epilogue B: X_{t+1} (premultiplied) -> XBf ----
        float* XBf = part;
        {
            const int j = tid & 127;
            const int r = tid >> 7;
            const int jj = j & 63;
            const float* S = (j < 64) ? HNs : CNs;
            float bias = (j < 64) ? BL[128 + jj] : BL[192 + jj];
            float a0 = bias;
            const int swz = j & 7;
            #pragma unroll
            for (int kk = 0; kk < 8; kk++) {
                const int pc = ((kk ^ swz) << 3);
                uint4 w = *(const uint4*)&WL[W_G + j * 64 + pc];
                const unsigned* u = (const unsigned*)&w;
                const float* s0 = &S[r * 64 + kk * 8];
                #pragma unroll
                for (int q = 0; q < 4; q++)
                    a0 += blo(u[q]) * s0[2*q] + bhi(u[q]) * s0[2*q+1];
            }
            XBf[j * 9 + r] = a0;
        }
        __syncthreads();

        // ---- store X_{t+1}^T: 8B agent-scope stores ----
        if (tid < 256) {
            const int j    = tid >> 1;
            const int half = tid & 1;
            const float* Xb = &XBf[j * 9 + half * 4];
            unsigned long long v =  (unsigned long long)f2bf(Xb[0])
                                 | ((unsigned long long)f2bf(Xb[1]) << 16)
                                 | ((unsigned long long)f2bf(Xb[2]) << 32)
                                 | ((unsigned long long)f2bf(Xb[3]) << 48);
            __hip_atomic_store((unsigned long long*)(Xn + (size_t)j * N_ + brow + half * 4),
                               v, __ATOMIC_RELAXED, __HIP_MEMORY_SCOPE_AGENT);
        }
        __syncthreads();   // drains X stores (vmcnt 0 before s_barrier)

        // ---- arrive (2-level tree), then hide latency under epilogue C ----
        if (tid == 0) {
            unsigned old = __hip_atomic_fetch_add(grpc, 1u, __ATOMIC_RELAXED,
                                                  __HIP_MEMORY_SCOPE_AGENT);
            if (old == 16u * (unsigned)(t + 1) - 1u)   // last of group this step
                __hip_atomic_fetch_add(root, 1u, __ATOMIC_RELAXED,
                                       __HIP_MEMORY_SCOPE_AGENT);
        }

        // ---- epilogue C: h_lstm/c_lstm for t+1 -> HLs/CLs ----
        if (tid < 512) {
            const int c = tid & 63;
            const int r = tid >> 6;
            float z[4];
            #pragma unroll
            for (int g = 0; g < 4; g++) z[g] = BL[256 + g * 64 + c];
            const int swz1 = c & 1, swz = c & 7;
            #pragma unroll
            for (int g = 0; g < 4; g++) {
                const ushort_t* Krow = Wblob + W_K + (g * 64 + c) * 16;  // GLOBAL (L2-hot)
                #pragma unroll
                for (int dd = 0; dd < 2; dd++) {
                    const int pc = ((dd ^ swz1) << 3);
                    uint4 w = *(const uint4*)&Krow[pc];
                    const unsigned* u = (const unsigned*)&w;
                    const float* xb = &XSs[r * 16 + dd * 8];
                    #pragma unroll
                    for (int q = 0; q < 4; q++)
                        z[g] += blo(u[q]) * xb[2*q] + bhi(u[q]) * xb[2*q+1];
                }
                const ushort_t* Rrow = &WL[W_R + (g * 64 + c) * 64];
                #pragma unroll
                for (int kk = 0; kk < 8; kk++) {
                    const int pc = ((kk ^ swz) << 3);
                    uint4 w = *(const uint4*)&Rrow[pc];
                    const unsigned* u = (const unsigned*)&w;
                    const float* hb = &HNs[r * 64 + kk * 8];
                    #pragma unroll
                    for (int q = 0; q < 4; q++)
                        z[g] += blo(u[q]) * hb[2*q] + bhi(u[q]) * hb[2*q+1];
                }
            }
            float clv = sig_(z[1]) * CNs[r * 64 + c] + sig_(z[0]) * tanh_(z[2]);
            float hlv = sig_(z[3]) * tanh_(clv);
            CLs[r * 64 + c] = clv;
            HLs[r * 64 + c] = hlv;
        }

        // ---- poll root ----
        if (tid == 0) {
            const unsigned target = 16u * (unsigned)(t + 1);
            while (__hip_atomic_load(root, __ATOMIC_RELAXED, __HIP_MEMORY_SCOPE_AGENT) < target)
                __builtin_amdgcn_s_sleep(1);
        }
        __syncthreads();
        asm volatile("" ::: "memory");
    }
}

extern "C" void kernel_launch(void* const* d_in, const int* in_sizes, int n_in,
                              void* d_out, int out_size, void* d_ws, size_t ws_size,
                              hipStream_t stream) {
    const float* xin = (const float*)d_in[0];
    const float* h0  = (const float*)d_in[1];
    const float* c0  = (const float*)d_in[2];
    const float* A   = (const float*)d_in[3];
    const float* Wgh = (const float*)d_in[4];
    const float* bgh = (const float*)d_in[5];
    const float* Wgc = (const float*)d_in[6];
    const float* bgc = (const float*)d_in[7];
    const float* Whc = (const float*)d_in[8];
    const float* Whp = (const float*)d_in[9];
    const float* bh  = (const float*)d_in[10];
    const float* Wcc = (const float*)d_in[11];
    const float* Wcp = (const float*)d_in[12];
    const float* bc  = (const float*)d_in[13];
    const float* K   = (const float*)d_in[14];
    const float* R   = (const float*)d_in[15];
    const float* bl  = (const float*)d_in[16];

    const size_t fixed = (size_t)N_ * N_ * 2
                       + (size_t)N_ * H_ * 4 * 2
                       + BLOB_BYTES + 4096;
    const size_t slot_bytes = SLOT_USH * 2;
    const bool deep = ws_size >= fixed + (size_t)(T_ + 1) * slot_bytes;
    const int nslots = deep ? (T_ + 1) : 2;

    char* w = (char*)d_ws;
    ushort_t* Abf  = (ushort_t*)w;  w += (size_t)N_ * N_ * 2;
    ushort_t* Xs   = (ushort_t*)w;  w += (size_t)nslots * slot_bytes;
    float* hl      = (float*)w;     w += (size_t)N_ * H_ * 4;
    float* cl      = (float*)w;     w += (size_t)N_ * H_ * 4;
    ushort_t* blob = (ushort_t*)w;  w += BLOB_BYTES;
    unsigned* cnt  = (unsigned*)w;  w += 4096;

    float* oh = (float*)d_out;
    float* oc = oh + (size_t)N_ * T_ * H_;

    convert_A_kernel<<<(N_ * N_) / (256 * 4), 256, 0, stream>>>(A, Abf, cnt);
    convert_W_kernel<<<16, 256, 0, stream>>>(Whc, Whp, Wcc, Wcp, Wgh, Wgc, R, K,
                                             bh, bc, bgh, bgc, bl, blob);
    prologue_kernel<<<N_, 64, 0, stream>>>(xin, h0, c0, Wgh, bgh, Wgc, bgc,
                                           K, R, bl, Xs, hl, cl);

    void* args[] = { (void*)&Abf, (void*)&Xs, (void*)&hl, (void*)&cl,
                     (void*)&xin, (void*)&blob, (void*)&oh, (void*)&oc, (void*)&cnt };
    if (deep)
        hipLaunchCooperativeKernel((const void*)persistent_kernel<true>,
                                   dim3(NBLK), dim3(NTHR), args, 0, stream);
    else
        hipLaunchCooperativeKernel((const void*)persistent_kernel<false>,
                                   dim3(NBLK), dim3(NTHR), args, 0, stream);
}

// Round 18
// 5287.412 us; speedup vs baseline: 1.4616x; 1.4616x over previous
//
#include <hip/hip_runtime.h>
#include <math.h>

#define N_  2048
#define T_  200
#define D_  16
#define H_  64
#define C2_ 128
#define BM  8
#define NTHR 1024
#define NBLK 256

// X slot: [128][2048] bf16 + 4KB guard gap
#define SLOT_USH ((size_t)C2_ * N_ + 2048)

typedef unsigned short ushort_t;
typedef short bf16x8 __attribute__((ext_vector_type(8)));
typedef float f32x4 __attribute__((ext_vector_type(4)));

// ---- weight blob layout (ushort offsets) ----
#define W_HC 0        // W_h_cur^T  [64][64]  swz8
#define W_HP 4096     // W_h_prev^T [64][64]  swz8
#define W_CC 8192     // W_c_cur^T  [64][64]  swz8
#define W_CP 12288    // W_c_prev^T [64][64]  swz8
#define W_G  16384    // [Wgh^T ; Wgc^T] [128][64] swz8
#define W_R  24576    // R^T [256][64] swz8
#define W_K  40960    // K^T [256][16] swz2  (read from GLOBAL in epiC)
#define W_USH 45056   // then 512 fp32 biases
#define BLOB_BYTES 92160

__device__ __forceinline__ float sig_(float x) {
    return __fdividef(1.0f, 1.0f + __expf(-x));
}
__device__ __forceinline__ float tanh_(float x) {
    float e = __expf(-2.0f * fabsf(x));
    float t = __fdividef(1.0f - e, 1.0f + e);
    return copysignf(t, x);
}
__device__ __forceinline__ ushort_t f2bf(float f) {
    unsigned u = __float_as_uint(f);
    u = (u + 0x7FFFu + ((u >> 16) & 1u)) >> 16;
    return (ushort_t)u;
}
__device__ __forceinline__ float blo(unsigned u){ return __uint_as_float(u << 16); }
__device__ __forceinline__ float bhi(unsigned u){ return __uint_as_float(u & 0xFFFF0000u); }

__device__ __forceinline__ void gload16(const void* g, void* l) {
    __builtin_amdgcn_global_load_lds(
        (const __attribute__((address_space(1))) unsigned int*)g,
        (__attribute__((address_space(3))) unsigned int*)l, 16, 0, 0);
}

// B-fragment load (DEEP: fresh-slot cached; else uncached agent-scope)
template<bool DEEP>
__device__ __forceinline__ bf16x8 ldB(const ushort_t* p) {
    if constexpr (DEEP) {
        return *(const bf16x8*)p;
    } else {
        union { unsigned long long q[2]; bf16x8 v; } u;
        u.q[0] = __hip_atomic_load((const unsigned long long*)p,
                                   __ATOMIC_RELAXED, __HIP_MEMORY_SCOPE_AGENT);
        u.q[1] = __hip_atomic_load(((const unsigned long long*)p) + 1,
                                   __ATOMIC_RELAXED, __HIP_MEMORY_SCOPE_AGENT);
        return u.v;
    }
}

// ---- A (fp32) -> A (bf16); zero all barrier counters (1024 slots) ----
__global__ __launch_bounds__(256) void convert_A_kernel(
    const float* __restrict__ A, ushort_t* __restrict__ Abf,
    unsigned* __restrict__ cnt)
{
    if (blockIdx.x == 0) {
        #pragma unroll
        for (int p = 0; p < 4; p++)
            __hip_atomic_store(cnt + p * 256 + threadIdx.x, 0u,
                               __ATOMIC_RELAXED, __HIP_MEMORY_SCOPE_AGENT);
    }
    size_t i = ((size_t)blockIdx.x * 256 + threadIdx.x) * 4;
    float4 v = *(const float4*)(A + i);
    ushort4 o;
    o.x = f2bf(v.x); o.y = f2bf(v.y); o.z = f2bf(v.z); o.w = f2bf(v.w);
    *(ushort4*)(Abf + i) = o;
}

// ---- pack weights: bf16, transposed, XOR-swizzled 16B chunks ----
__global__ __launch_bounds__(256) void convert_W_kernel(
    const float* __restrict__ Whc, const float* __restrict__ Whp,
    const float* __restrict__ Wcc, const float* __restrict__ Wcp,
    const float* __restrict__ Wgh, const float* __restrict__ Wgc,
    const float* __restrict__ R,   const float* __restrict__ Kw,
    const float* __restrict__ bh,  const float* __restrict__ bc,
    const float* __restrict__ bgh, const float* __restrict__ bgc,
    const float* __restrict__ bl,
    ushort_t* __restrict__ blob)
{
    const int stride = gridDim.x * 256;
    const int gid = blockIdx.x * 256 + threadIdx.x;
    for (int idx = gid; idx < 4096; idx += stride) {
        int k = idx >> 6, c = idx & 63;
        int dst = c * 64 + ((((k >> 3) ^ c) & 7) << 3) + (k & 7);
        blob[W_HC + dst] = f2bf(Whc[idx]);
        blob[W_HP + dst] = f2bf(Whp[idx]);
        blob[W_CC + dst] = f2bf(Wcc[idx]);
        blob[W_CP + dst] = f2bf(Wcp[idx]);
        blob[W_G + dst]        = f2bf(Wgh[idx]);
        blob[W_G + 4096 + dst] = f2bf(Wgc[idx]);
    }
    for (int idx = gid; idx < 16384; idx += stride) {
        int k = idx >> 8, gc = idx & 255;
        int dst = gc * 64 + ((((k >> 3) ^ gc) & 7) << 3) + (k & 7);
        blob[W_R + dst] = f2bf(R[idx]);
    }
    for (int idx = gid; idx < 4096; idx += stride) {
        int d = idx >> 8, gc = idx & 255;
        int dst = gc * 16 + ((((d >> 3) ^ gc) & 1) << 3) + (d & 7);
        blob[W_K + dst] = f2bf(Kw[idx]);
    }
    float* bf = (float*)(blob + W_USH);
    if (gid < 64) { bf[gid] = bh[gid]; bf[64+gid] = bc[gid]; bf[128+gid] = bgh[gid]; bf[192+gid] = bgc[gid]; }
    if (gid < 256) bf[256 + gid] = bl[gid];
}

// ---- Prologue: X_0^T (premultiplied, bf16, slot 0), h_lstm_0, c_lstm_0 ----
__global__ __launch_bounds__(64) void prologue_kernel(
    const float* __restrict__ xin, const float* __restrict__ h0,
    const float* __restrict__ c0,
    const float* __restrict__ Wgh, const float* __restrict__ bgh,
    const float* __restrict__ Wgc, const float* __restrict__ bgc,
    const float* __restrict__ K, const float* __restrict__ R,
    const float* __restrict__ bl,
    ushort_t* __restrict__ Xt, float* __restrict__ hl, float* __restrict__ cl)
{
    const int n = blockIdx.x;
    const int j = threadIdx.x;
    __shared__ float hs[H_], cs[H_], xs[D_];
    hs[j] = h0[n * H_ + j];
    cs[j] = c0[n * H_ + j];
    if (j < D_) xs[j] = xin[(size_t)n * T_ * D_ + j];
    __syncthreads();

    float xh = bgh[j], xc = bgc[j];
    for (int k = 0; k < H_; k++) {
        xh += hs[k] * Wgh[k * H_ + j];
        xc += cs[k] * Wgc[k * H_ + j];
    }
    Xt[(size_t)j * N_ + n]        = f2bf(xh);
    Xt[(size_t)(H_ + j) * N_ + n] = f2bf(xc);

    float zi = bl[j], zf = bl[H_ + j], zg = bl[2 * H_ + j], zo = bl[3 * H_ + j];
    for (int d = 0; d < D_; d++) {
        float xv = xs[d];
        zi += xv * K[d * 256 + j];
        zf += xv * K[d * 256 + 64 + j];
        zg += xv * K[d * 256 + 128 + j];
        zo += xv * K[d * 256 + 192 + j];
    }
    for (int k = 0; k < H_; k++) {
        float hv = hs[k];
        zi += hv * R[k * 256 + j];
        zf += hv * R[k * 256 + 64 + j];
        zg += hv * R[k * 256 + 128 + j];
        zo += hv * R[k * 256 + 192 + j];
    }
    float clv = sig_(zf) * cs[j] + sig_(zi) * tanh_(zg);
    float hlv = sig_(zo) * tanh_(clv);
    cl[n * H_ + j] = clv;
    hl[n * H_ + j] = hlv;
}

// ---- Persistent kernel (R15 + per-k-quarter producer/consumer gating) ----
// counters: quarter-roots at cnt[q*32] (q=0..3); group counters at cnt[128+g*32]
template<bool DEEP>
__global__ __launch_bounds__(NTHR, 4) void persistent_kernel(
    const ushort_t* __restrict__ Abf,
    ushort_t* __restrict__ Xs,
    const float* __restrict__ hl, const float* __restrict__ clm,
    const float* __restrict__ xin,
    const ushort_t* __restrict__ Wblob,
    float* __restrict__ oh, float* __restrict__ oc,
    unsigned* __restrict__ cnt)
{
    __shared__ __align__(16) ushort_t WL[46080];     // 90 KB weights+biases
    __shared__ __align__(16) ushort_t Alds[BM * N_]; // 32 KB A-panel, chunk-swizzled
    __shared__ __align__(16) float HLs[BM * H_], CLs[BM * H_];
    __shared__ __align__(16) float XSs[BM * D_];
    __shared__ __align__(16) float part[4 * BM * C2_];   // 16 KB; aliased as XBf
    __shared__ __align__(16) float Gs[BM * C2_];
    __shared__ __align__(16) float HNs[BM * H_], CNs[BM * H_];

    const int tid  = threadIdx.x;
    const int brow = blockIdx.x * BM;
    const int wave = tid >> 6;
    const int lane = tid & 63;

    unsigned* grpc  = cnt + 128 + (blockIdx.x >> 4) * 32;  // 16-block tree group
    unsigned* qroot = cnt + (blockIdx.x >> 6) * 32;        // this block's producer quarter

    // ---- one-time staging: weights + state ----
    {
        const char* gsrc = (const char*)Wblob;
        char* lbase = (char*)WL;
        for (int i = wave; i < 90; i += 16)
            gload16(gsrc + i * 1024 + lane * 16, lbase + i * 1024);
        if (wave == 0) {
            gload16((const char*)(hl + (size_t)brow * H_) + lane * 16, (char*)HLs);
            gload16((const char*)(hl + (size_t)brow * H_) + 1024 + lane * 16, (char*)HLs + 1024);
        }
        if (wave == 1) {
            gload16((const char*)(clm + (size_t)brow * H_) + lane * 16, (char*)CLs);
            gload16((const char*)(clm + (size_t)brow * H_) + 1024 + lane * 16, (char*)CLs + 1024);
        }
    }
    // ---- one-time: A-panel -> LDS, 16B-chunk XOR swizzle ----
    for (int idx = tid; idx < BM * 256; idx += NTHR) {
        int row = idx >> 8;
        int kc  = idx & 255;
        bf16x8 v = *(const bf16x8*)(Abf + (size_t)(brow + row) * N_ + kc * 8);
        int swzc = (kc & ~7) | ((kc ^ row) & 7);
        *(bf16x8*)((char*)Alds + row * 4096 + swzc * 16) = v;
    }
    __syncthreads();

    const float* BL = (const float*)(WL + W_USH);

    for (int t = 0; t < T_; t++) {
        const ushort_t* Xc = Xs + (size_t)(DEEP ? t : (t & 1)) * SLOT_USH;
        ushort_t*       Xn = Xs + (size_t)(DEEP ? (t + 1) : ((t + 1) & 1)) * SLOT_USH;

        // align block (all waves past previous epilogue C / XSs consumers)
        __syncthreads();

        // prefetch x_{t+1} (drains at the post-GEMM barrier)
        if (t + 1 < T_ && wave == 7 && lane < 32) {
            const float* g = xin + (size_t)(brow + (lane >> 2)) * (T_ * D_)
                                 + (size_t)(t + 1) * D_ + (lane & 3) * 4;
            gload16(g, (char*)XSs);
        }

        // ---- quarter gate: wave-group wg waits only for its k-quarter ----
        {
            const int wg = wave >> 2;
            const int q  = (wg + blockIdx.x) & 3;
            if (t > 0 && lane == 0) {
                const unsigned target = 4u * (unsigned)t;
                while (__hip_atomic_load(cnt + q * 32, __ATOMIC_RELAXED,
                                         __HIP_MEMORY_SCOPE_AGENT) < target)
                    __builtin_amdgcn_s_sleep(1);
            }
            asm volatile("" ::: "memory");
        }

        // ---- GEMM: 16 waves = 4 col-tiles x 4 k-quarters (block-rotated);
        //      two-pass burst-16 B-loads; A from LDS ----
        {
            const int ct = (wave & 3) * 32;
            const int kq = ((((wave >> 2) + blockIdx.x) & 3)) * 512;
            const int fr = lane & 15;
            const int kg = lane >> 4;
            const int arow = fr & 7;
            const int kcb = (kq >> 3) + kg;
            const ushort_t* Bp0 = Xc + (size_t)(ct + fr) * N_ + kq + kg * 8;
            const ushort_t* Bp1 = Bp0 + (size_t)16 * N_;
            f32x4 acc0 = {0.f, 0.f, 0.f, 0.f}, acc1 = {0.f, 0.f, 0.f, 0.f};

            bf16x8 rb[16];
            #pragma unroll
            for (int kk = 0; kk < 16; kk++) rb[kk] = ldB<DEEP>(Bp0 + kk * 32);
            #pragma unroll
            for (int kk = 0; kk < 16; kk++) {
                const int kc  = kcb + kk * 4;
                const int swzc = (kc & ~7) | ((kc ^ arow) & 7);
                bf16x8 a = *(const bf16x8*)((const char*)Alds + arow * 4096 + swzc * 16);
                acc0 = __builtin_amdgcn_mfma_f32_16x16x32_bf16(a, rb[kk], acc0, 0, 0, 0);
            }
            #pragma unroll
            for (int kk = 0; kk < 16; kk++) rb[kk] = ldB<DEEP>(Bp1 + kk * 32);
            #pragma unroll
            for (int kk = 0; kk < 16; kk++) {
                const int kc  = kcb + kk * 4;
                const int swzc = (kc & ~7) | ((kc ^ arow) & 7);
                bf16x8 a = *(const bf16x8*)((const char*)Alds + arow * 4096 + swzc * 16);
                acc1 = __builtin_amdgcn_mfma_f32_16x16x32_bf16(a, rb[kk], acc1, 0, 0, 0);
            }
            if (kg < 2) {
                float* pp = &part[(wave >> 2) * (BM * C2_) + ct];
                const int rb4 = kg * 4;
                #pragma unroll
                for (int r = 0; r < 4; r++) {
                    pp[(rb4 + r) * C2_ + fr]      = acc0[r];
                    pp[(rb4 + r) * C2_ + 16 + fr] = acc1[r];
                }
            }
        }
        __syncthreads();

        // ---- reduce 4 k-partials + tanh -> Gs ----
        Gs[tid] = tanh_(part[tid] + part[1024 + tid] + part[2048 + tid] + part[3072 + tid]);
        __syncthreads();

        // ---- epilogue A: h_new / c_new + output store ----
        if (tid < 512) {
            const int c = tid & 63;
            const int r = tid >> 6;
            const int swz = c & 7;
            float ah = BL[c], ac = BL[64 + c];
            #pragma unroll
            for (int kk = 0; kk < 8; kk++) {
                const int pc = ((kk ^ swz) << 3);
                uint4 w1 = *(const uint4*)&WL[W_HC + c * 64 + pc];
                uint4 w2 = *(const uint4*)&WL[W_HP + c * 64 + pc];
                uint4 w3 = *(const uint4*)&WL[W_CC + c * 64 + pc];
                uint4 w4 = *(const uint4*)&WL[W_CP + c * 64 + pc];
                const float* hb = &HLs[r * 64 + kk * 8];
                const float* gh = &Gs[r * 128 + kk * 8];
                const float* cb = &CLs[r * 64 + kk * 8];
                const float* gc = &Gs[r * 128 + 64 + kk * 8];
                const unsigned* u1 = (const unsigned*)&w1;
                const unsigned* u2 = (const unsigned*)&w2;
                const unsigned* u3 = (const unsigned*)&w3;
                const unsigned* u4 = (const unsigned*)&w4;
                #pragma unroll
                for (int q = 0; q < 4; q++) {
                    ah += blo(u1[q]) * hb[2*q] + bhi(u1[q]) * hb[2*q+1];
                    ah += blo(u2[q]) * gh[2*q] + bhi(u2[q]) * gh[2*q+1];
                    ac += blo(u3[q]) * cb[2*q] + bhi(u3[q]) * cb[2*q+1];
                    ac += blo(u4[q]) * gc[2*q] + bhi(u4[q]) * gc[2*q+1];
                }
            }
            float hnv = sig_(ah), cnv = sig_(ac);
            HNs[r * 64 + c] = hnv;
            CNs[r * 64 + c] = cnv;
            size_t o = (size_t)(brow + r) * (T_ * H_) + (size_t)t * H_ + c;
            oh[o] = hnv;
            oc[o] = cnv;
        }

        if (t + 1 == T_) break;
        __syncthreads();

        // ---- epilogue B: X_{t+1} (premultiplied) -> XBf ----
        float* XBf = part;
        {
            const int j = tid & 127;
            const int r = tid >> 7;
            const int jj = j & 63;
            const float* S = (j < 64) ? HNs : CNs;
            float bias = (j < 64) ? BL[128 + jj] : BL[192 + jj];
            float a0 = bias;
            const int swz = j & 7;
            #pragma unroll
            for (int kk = 0; kk < 8; kk++) {
                const int pc = ((kk ^ swz) << 3);
                uint4 w = *(const uint4*)&WL[W_G + j * 64 + pc];
                const unsigned* u = (const unsigned*)&w;
                const float* s0 = &S[r * 64 + kk * 8];
                #pragma unroll
                for (int q = 0; q < 4; q++)
                    a0 += blo(u[q]) * s0[2*q] + bhi(u[q]) * s0[2*q+1];
            }
            XBf[j * 9 + r] = a0;
        }
        __syncthreads();

        // ---- store X_{t+1}^T: 8B agent-scope stores ----
        if (tid < 256) {
            const int j    = tid >> 1;
            const int half = tid & 1;
            const float* Xb = &XBf[j * 9 + half * 4];
            unsigned long long v =  (unsigned long long)f2bf(Xb[0])
                                 | ((unsigned long long)f2bf(Xb[1]) << 16)
                                 | ((unsigned long long)f2bf(Xb[2]) << 32)
                                 | ((unsigned long long)f2bf(Xb[3]) << 48);
            __hip_atomic_store((unsigned long long*)(Xn + (size_t)j * N_ + brow + half * 4),
                               v, __ATOMIC_RELAXED, __HIP_MEMORY_SCOPE_AGENT);
        }
        __syncthreads();   // drains X stores (vmcnt 0 before s_barrier)

        // ---- arrive: group counter -> (last of 16) quarter-root ----
        if (tid == 0) {
            unsigned old = __hip_atomic_fetch_add(grpc, 1u, __ATOMIC_RELAXED,
                                                  __HIP_MEMORY_SCOPE_AGENT);
            if (old == 16u * (unsigned)(t + 1) - 1u)
                __hip_atomic_fetch_add(qroot, 1u, __ATOMIC_RELAXED,
                                       __HIP_MEMORY_SCOPE_AGENT);
        }

        // ---- epilogue C: h_lstm/c_lstm for t+1 -> HLs/CLs ----
        if (tid < 512) {
            const int c = tid & 63;
            const int r = tid >> 6;
            float z[4];
            #pragma unroll
            for (int g = 0; g < 4; g++) z[g] = BL[256 + g * 64 + c];
            const int swz1 = c & 1, swz = c & 7;
            #pragma unroll
            for (int g = 0; g < 4; g++) {
                const ushort_t* Krow = Wblob + W_K + (g * 64 + c) * 16;  // GLOBAL (L2-hot)
                #pragma unroll
                for (int dd = 0; dd < 2; dd++) {
                    const int pc = ((dd ^ swz1) << 3);
                    uint4 w = *(const uint4*)&Krow[pc];
                    const unsigned* u = (const unsigned*)&w;
                    const float* xb = &XSs[r * 16 + dd * 8];
                    #pragma unroll
                    for (int q = 0; q < 4; q++)
                        z[g] += blo(u[q]) * xb[2*q] + bhi(u[q]) * xb[2*q+1];
                }
                const ushort_t* Rrow = &WL[W_R + (g * 64 + c) * 64];
                #pragma unroll
                for (int kk = 0; kk < 8; kk++) {
                    const int pc = ((kk ^ swz) << 3);
                    uint4 w = *(const uint4*)&Rrow[pc];
                    const unsigned* u = (const unsigned*)&w;
                    const float* hb = &HNs[r * 64 + kk * 8];
                    #pragma unroll
                    for (int q = 0; q < 4; q++)
                        z[g] += blo(u[q]) * hb[2*q] + bhi(u[q]) * hb[2*q+1];
                }
            }
            float clv = sig_(z[1]) * CNs[r * 64 + c] + sig_(z[0]) * tanh_(z[2]);
            float hlv = sig_(z[3]) * tanh_(clv);
            CLs[r * 64 + c] = clv;
            HLs[r * 64 + c] = hlv;
        }
        // (no global poll here — next iteration's quarter gates do the waiting)
    }
}

extern "C" void kernel_launch(void* const* d_in, const int* in_sizes, int n_in,
                              void* d_out, int out_size, void* d_ws, size_t ws_size,
                              hipStream_t stream) {
    const float* xin = (const float*)d_in[0];
    const float* h0  = (const float*)d_in[1];
    const float* c0  = (const float*)d_in[2];
    const float* A   = (const float*)d_in[3];
    const float* Wgh = (const float*)d_in[4];
    const float* bgh = (const float*)d_in[5];
    const float* Wgc = (const float*)d_in[6];
    const float* bgc = (const float*)d_in[7];
    const float* Whc = (const float*)d_in[8];
    const float* Whp = (const float*)d_in[9];
    const float* bh  = (const float*)d_in[10];
    const float* Wcc = (const float*)d_in[11];
    const float* Wcp = (const float*)d_in[12];
    const float* bc  = (const float*)d_in[13];
    const float* K   = (const float*)d_in[14];
    const float* R   = (const float*)d_in[15];
    const float* bl  = (const float*)d_in[16];

    const size_t fixed = (size_t)N_ * N_ * 2
                       + (size_t)N_ * H_ * 4 * 2
                       + BLOB_BYTES + 4096;
    const size_t slot_bytes = SLOT_USH * 2;
    const bool deep = ws_size >= fixed + (size_t)(T_ + 1) * slot_bytes;
    const int nslots = deep ? (T_ + 1) : 2;

    char* w = (char*)d_ws;
    ushort_t* Abf  = (ushort_t*)w;  w += (size_t)N_ * N_ * 2;
    ushort_t* Xs   = (ushort_t*)w;  w += (size_t)nslots * slot_bytes;
    float* hl      = (float*)w;     w += (size_t)N_ * H_ * 4;
    float* cl      = (float*)w;     w += (size_t)N_ * H_ * 4;
    ushort_t* blob = (ushort_t*)w;  w += BLOB_BYTES;
    unsigned* cnt  = (unsigned*)w;  w += 4096;

    float* oh = (float*)d_out;
    float* oc = oh + (size_t)N_ * T_ * H_;

    convert_A_kernel<<<(N_ * N_) / (256 * 4), 256, 0, stream>>>(A, Abf, cnt);
    convert_W_kernel<<<16, 256, 0, stream>>>(Whc, Whp, Wcc, Wcp, Wgh, Wgc, R, K,
                                             bh, bc, bgh, bgc, bl, blob);
    prologue_kernel<<<N_, 64, 0, stream>>>(xin, h0, c0, Wgh, bgh, Wgc, bgc,
                                           K, R, bl, Xs, hl, cl);

    void* args[] = { (void*)&Abf, (void*)&Xs, (void*)&hl, (void*)&cl,
                     (void*)&xin, (void*)&blob, (void*)&oh, (void*)&oc, (void*)&cnt };
    if (deep)
        hipLaunchCooperativeKernel((const void*)persistent_kernel<true>,
                                   dim3(NBLK), dim3(NTHR), args, 0, stream);
    else
        hipLaunchCooperativeKernel((const void*)persistent_kernel<false>,
                                   dim3(NBLK), dim3(NTHR), args, 0, stream);
}

// Round 19
// 3525.808 us; speedup vs baseline: 2.1918x; 1.4996x over previous
//
#include <hip/hip_runtime.h>
#include <math.h>

#define N_  2048
#define T_  200
#define D_  16
#define H_  64
#define C2_ 128
#define BM  8
#define NTHR 1024
#define NBLK 256

// X slot: [128][2048] i8 + 4KB guard gap (bytes)
#define SLOT_BYTES ((size_t)C2_ * N_ + 4096)

#define SA_ 130048.0f   // A scale: 127 / (2/2048)
#define SX_ 32.0f       // X scale
#define INV_ (1.0f / (130048.0f * 32.0f))

typedef unsigned short ushort_t;
typedef signed char i8_t;
typedef int i32x4 __attribute__((ext_vector_type(4)));
typedef float f32x4 __attribute__((ext_vector_type(4)));

// ---- weight blob layout (ushort offsets) ----
#define W_HC 0        // W_h_cur^T  [64][64]  swz8
#define W_HP 4096     // W_h_prev^T [64][64]  swz8
#define W_CC 8192     // W_c_cur^T  [64][64]  swz8
#define W_CP 12288    // W_c_prev^T [64][64]  swz8
#define W_G  16384    // [Wgh^T ; Wgc^T] [128][64] swz8
#define W_R  24576    // R^T [256][64] swz8
#define W_K  40960    // K^T [256][16] swz2  (read from GLOBAL in epiC)
#define W_USH 45056   // then 512 fp32 biases
#define BLOB_BYTES 92160

__device__ __forceinline__ float sig_(float x) {
    return __fdividef(1.0f, 1.0f + __expf(-x));
}
__device__ __forceinline__ float tanh_(float x) {
    float e = __expf(-2.0f * fabsf(x));
    float t = __fdividef(1.0f - e, 1.0f + e);
    return copysignf(t, x);
}
__device__ __forceinline__ ushort_t f2bf(float f) {
    unsigned u = __float_as_uint(f);
    u = (u + 0x7FFFu + ((u >> 16) & 1u)) >> 16;
    return (ushort_t)u;
}
__device__ __forceinline__ float blo(unsigned u){ return __uint_as_float(u << 16); }
__device__ __forceinline__ float bhi(unsigned u){ return __uint_as_float(u & 0xFFFF0000u); }
__device__ __forceinline__ i8_t q8_(float x, float s) {
    float v = fminf(fmaxf(x * s, -127.0f), 127.0f);
    return (i8_t)__float2int_rn(v);
}

__device__ __forceinline__ void gload16(const void* g, void* l) {
    __builtin_amdgcn_global_load_lds(
        (const __attribute__((address_space(1))) unsigned int*)g,
        (__attribute__((address_space(3))) unsigned int*)l, 16, 0, 0);
}

// B-fragment load, 16 i8 (DEEP: fresh-slot cached; else uncached agent-scope)
template<bool DEEP>
__device__ __forceinline__ i32x4 ldB8(const i8_t* p) {
    if constexpr (DEEP) {
        return *(const i32x4*)p;
    } else {
        union { unsigned long long q[2]; i32x4 v; } u;
        u.q[0] = __hip_atomic_load((const unsigned long long*)p,
                                   __ATOMIC_RELAXED, __HIP_MEMORY_SCOPE_AGENT);
        u.q[1] = __hip_atomic_load(((const unsigned long long*)p) + 1,
                                   __ATOMIC_RELAXED, __HIP_MEMORY_SCOPE_AGENT);
        return u.v;
    }
}

// ---- A (fp32) -> A (i8, scale SA_); zero all barrier counters ----
__global__ __launch_bounds__(256) void convert_A_kernel(
    const float* __restrict__ A, i8_t* __restrict__ Ab8,
    unsigned* __restrict__ cnt)
{
    if (blockIdx.x == 0) {
        #pragma unroll
        for (int p = 0; p < 4; p++)
            __hip_atomic_store(cnt + p * 256 + threadIdx.x, 0u,
                               __ATOMIC_RELAXED, __HIP_MEMORY_SCOPE_AGENT);
    }
    size_t i = ((size_t)blockIdx.x * 256 + threadIdx.x) * 4;
    float4 v = *(const float4*)(A + i);
    uchar4 o;
    o.x = (unsigned char)q8_(v.x, SA_);
    o.y = (unsigned char)q8_(v.y, SA_);
    o.z = (unsigned char)q8_(v.z, SA_);
    o.w = (unsigned char)q8_(v.w, SA_);
    *(uchar4*)(Ab8 + i) = o;
}

// ---- pack weights: bf16, transposed, XOR-swizzled 16B chunks ----
__global__ __launch_bounds__(256) void convert_W_kernel(
    const float* __restrict__ Whc, const float* __restrict__ Whp,
    const float* __restrict__ Wcc, const float* __restrict__ Wcp,
    const float* __restrict__ Wgh, const float* __restrict__ Wgc,
    const float* __restrict__ R,   const float* __restrict__ Kw,
    const float* __restrict__ bh,  const float* __restrict__ bc,
    const float* __restrict__ bgh, const float* __restrict__ bgc,
    const float* __restrict__ bl,
    ushort_t* __restrict__ blob)
{
    const int stride = gridDim.x * 256;
    const int gid = blockIdx.x * 256 + threadIdx.x;
    for (int idx = gid; idx < 4096; idx += stride) {
        int k = idx >> 6, c = idx & 63;
        int dst = c * 64 + ((((k >> 3) ^ c) & 7) << 3) + (k & 7);
        blob[W_HC + dst] = f2bf(Whc[idx]);
        blob[W_HP + dst] = f2bf(Whp[idx]);
        blob[W_CC + dst] = f2bf(Wcc[idx]);
        blob[W_CP + dst] = f2bf(Wcp[idx]);
        blob[W_G + dst]        = f2bf(Wgh[idx]);
        blob[W_G + 4096 + dst] = f2bf(Wgc[idx]);
    }
    for (int idx = gid; idx < 16384; idx += stride) {
        int k = idx >> 8, gc = idx & 255;
        int dst = gc * 64 + ((((k >> 3) ^ gc) & 7) << 3) + (k & 7);
        blob[W_R + dst] = f2bf(R[idx]);
    }
    for (int idx = gid; idx < 4096; idx += stride) {
        int d = idx >> 8, gc = idx & 255;
        int dst = gc * 16 + ((((d >> 3) ^ gc) & 1) << 3) + (d & 7);
        blob[W_K + dst] = f2bf(Kw[idx]);
    }
    float* bf = (float*)(blob + W_USH);
    if (gid < 64) { bf[gid] = bh[gid]; bf[64+gid] = bc[gid]; bf[128+gid] = bgh[gid]; bf[192+gid] = bgc[gid]; }
    if (gid < 256) bf[256 + gid] = bl[gid];
}

// ---- Prologue: X_0^T (premultiplied, i8, slot 0), h_lstm_0, c_lstm_0 ----
__global__ __launch_bounds__(64) void prologue_kernel(
    const float* __restrict__ xin, const float* __restrict__ h0,
    const float* __restrict__ c0,
    const float* __restrict__ Wgh, const float* __restrict__ bgh,
    const float* __restrict__ Wgc, const float* __restrict__ bgc,
    const float* __restrict__ K, const float* __restrict__ R,
    const float* __restrict__ bl,
    i8_t* __restrict__ Xt, float* __restrict__ hl, float* __restrict__ cl)
{
    const int n = blockIdx.x;
    const int j = threadIdx.x;
    __shared__ float hs[H_], cs[H_], xs[D_];
    hs[j] = h0[n * H_ + j];
    cs[j] = c0[n * H_ + j];
    if (j < D_) xs[j] = xin[(size_t)n * T_ * D_ + j];
    __syncthreads();

    float xh = bgh[j], xc = bgc[j];
    for (int k = 0; k < H_; k++) {
        xh += hs[k] * Wgh[k * H_ + j];
        xc += cs[k] * Wgc[k * H_ + j];
    }
    Xt[(size_t)j * N_ + n]        = q8_(xh, SX_);
    Xt[(size_t)(H_ + j) * N_ + n] = q8_(xc, SX_);

    float zi = bl[j], zf = bl[H_ + j], zg = bl[2 * H_ + j], zo = bl[3 * H_ + j];
    for (int d = 0; d < D_; d++) {
        float xv = xs[d];
        zi += xv * K[d * 256 + j];
        zf += xv * K[d * 256 + 64 + j];
        zg += xv * K[d * 256 + 128 + j];
        zo += xv * K[d * 256 + 192 + j];
    }
    for (int k = 0; k < H_; k++) {
        float hv = hs[k];
        zi += hv * R[k * 256 + j];
        zf += hv * R[k * 256 + 64 + j];
        zg += hv * R[k * 256 + 128 + j];
        zo += hv * R[k * 256 + 192 + j];
    }
    float clv = sig_(zf) * cs[j] + sig_(zi) * tanh_(zg);
    float hlv = sig_(zo) * tanh_(clv);
    cl[n * H_ + j] = clv;
    hl[n * H_ + j] = hlv;
}

// ---- Persistent kernel (R15 structure; i8 GEMM) ----
template<bool DEEP>
__global__ __launch_bounds__(NTHR, 4) void persistent_kernel(
    const i8_t* __restrict__ Ab8,
    i8_t* __restrict__ Xs,
    const float* __restrict__ hl, const float* __restrict__ clm,
    const float* __restrict__ xin,
    const ushort_t* __restrict__ Wblob,
    float* __restrict__ oh, float* __restrict__ oc,
    unsigned* __restrict__ cnt)
{
    __shared__ __align__(16) ushort_t WL[46080];     // 90 KB weights+biases
    __shared__ __align__(16) i8_t Alds[BM * N_];     // 16 KB A-panel i8, chunk-swizzled
    __shared__ __align__(16) float HLs[BM * H_], CLs[BM * H_];
    __shared__ __align__(16) float XSs[BM * D_];
    __shared__ __align__(16) float part[4 * BM * C2_];   // 16 KB; aliased as XBf
    __shared__ __align__(16) float Gs[BM * C2_];
    __shared__ __align__(16) float HNs[BM * H_], CNs[BM * H_];

    const int tid  = threadIdx.x;
    const int brow = blockIdx.x * BM;
    const int wave = tid >> 6;
    const int lane = tid & 63;

    // barrier tree: root = cnt[0]; group g counter = cnt[32 + g*32]
    unsigned* grpc = cnt + 32 + (blockIdx.x >> 4) * 32;
    unsigned* root = cnt;

    // ---- one-time staging: weights + state ----
    {
        const char* gsrc = (const char*)Wblob;
        char* lbase = (char*)WL;
        for (int i = wave; i < 90; i += 16)
            gload16(gsrc + i * 1024 + lane * 16, lbase + i * 1024);
        if (wave == 0) {
            gload16((const char*)(hl + (size_t)brow * H_) + lane * 16, (char*)HLs);
            gload16((const char*)(hl + (size_t)brow * H_) + 1024 + lane * 16, (char*)HLs + 1024);
        }
        if (wave == 1) {
            gload16((const char*)(clm + (size_t)brow * H_) + lane * 16, (char*)CLs);
            gload16((const char*)(clm + (size_t)brow * H_) + 1024 + lane * 16, (char*)CLs + 1024);
        }
    }
    // ---- one-time: A-panel (i8) -> LDS, 16B-chunk XOR swizzle ----
    for (int idx = tid; idx < BM * 128; idx += NTHR) {   // 1024 chunks of 16B
        int row = idx >> 7;        // 0..7
        int kc  = idx & 127;       // chunk within row (16 i8 each)
        i32x4 v = *(const i32x4*)(Ab8 + (size_t)(brow + row) * N_ + kc * 16);
        int swzc = (kc & ~7) | ((kc ^ row) & 7);
        *(i32x4*)(Alds + row * 2048 + swzc * 16) = v;
    }
    __syncthreads();

    const float* BL = (const float*)(WL + W_USH);

    for (int t = 0; t < T_; t++) {
        const i8_t* Xc = Xs + (size_t)(DEEP ? t : (t & 1)) * SLOT_BYTES;
        i8_t*       Xn = Xs + (size_t)(DEEP ? (t + 1) : ((t + 1) & 1)) * SLOT_BYTES;

        // prefetch x_{t+1} (drains at next barrier)
        if (t + 1 < T_ && wave == 7 && lane < 32) {
            const float* g = xin + (size_t)(brow + (lane >> 2)) * (T_ * D_)
                                 + (size_t)(t + 1) * D_ + (lane & 3) * 4;
            gload16(g, (char*)XSs);
        }

        // ---- GEMM (i8): 16 waves = 4 col-tiles x 4 k-quarters (block-rotated);
        //      two-pass burst-8 B-loads; A from LDS; K=64 per MFMA ----
        {
            const int ct = (wave & 3) * 32;
            const int kq = ((((wave >> 2) + blockIdx.x) & 3)) * 512;  // per-block k-rotation
            const int fr = lane & 15;
            const int kg = lane >> 4;          // 0..3 -> k-sub 16 i8 each
            const int arow = fr & 7;
            const int kcb = (kq >> 4) + kg;    // 16B-chunk base index
            const i8_t* Bp0 = Xc + (size_t)(ct + fr) * N_ + kq + kg * 16;
            const i8_t* Bp1 = Bp0 + (size_t)16 * N_;
            i32x4 acc0 = {0, 0, 0, 0}, acc1 = {0, 0, 0, 0};

            i32x4 rb[8];
            #pragma unroll
            for (int kk = 0; kk < 8; kk++) rb[kk] = ldB8<DEEP>(Bp0 + kk * 64);
            #pragma unroll
            for (int kk = 0; kk < 8; kk++) {
                const int kc  = kcb + kk * 4;
                const int swzc = (kc & ~7) | ((kc ^ arow) & 7);
                i32x4 a = *(const i32x4*)(Alds + arow * 2048 + swzc * 16);
                acc0 = __builtin_amdgcn_mfma_i32_16x16x64_i8(a, rb[kk], acc0, 0, 0, 0);
            }
            #pragma unroll
            for (int kk = 0; kk < 8; kk++) rb[kk] = ldB8<DEEP>(Bp1 + kk * 64);
            #pragma unroll
            for (int kk = 0; kk < 8; kk++) {
                const int kc  = kcb + kk * 4;
                const int swzc = (kc & ~7) | ((kc ^ arow) & 7);
                i32x4 a = *(const i32x4*)(Alds + arow * 2048 + swzc * 16);
                acc1 = __builtin_amdgcn_mfma_i32_16x16x64_i8(a, rb[kk], acc1, 0, 0, 0);
            }
            if (kg < 2) {   // rows 8..15 duplicate 0..7 -> discard
                float* pp = &part[(wave >> 2) * (BM * C2_) + ct];
                const int rb4 = kg * 4;
                #pragma unroll
                for (int r = 0; r < 4; r++) {
                    pp[(rb4 + r) * C2_ + fr]      = (float)acc0[r] * INV_;
                    pp[(rb4 + r) * C2_ + 16 + fr] = (float)acc1[r] * INV_;
                }
            }
        }
        __syncthreads();

        // ---- reduce 4 k-partials + tanh -> Gs ----
        Gs[tid] = tanh_(part[tid] + part[1024 + tid] + part[2048 + tid] + part[3072 + tid]);
        __syncthreads();

        // ---- epilogue A: h_new / c_new + output store ----
        if (tid < 512) {
            const int c = tid & 63;
            const int r = tid >> 6;
            const int swz = c & 7;
            float ah = BL[c], ac = BL[64 + c];
            #pragma unroll
            for (int kk = 0; kk < 8; kk++) {
                const int pc = ((kk ^ swz) << 3);
                uint4 w1 = *(const uint4*)&WL[W_HC + c * 64 + pc];
                uint4 w2 = *(const uint4*)&WL[W_HP + c * 64 + pc];
                uint4 w3 = *(const uint4*)&WL[W_CC + c * 64 + pc];
                uint4 w4 = *(const uint4*)&WL[W_CP + c * 64 + pc];
                const float* hb = &HLs[r * 64 + kk * 8];
                const float* gh = &Gs[r * 128 + kk * 8];
                const float* cb = &CLs[r * 64 + kk * 8];
                const float* gc = &Gs[r * 128 + 64 + kk * 8];
                const unsigned* u1 = (const unsigned*)&w1;
                const unsigned* u2 = (const unsigned*)&w2;
                const unsigned* u3 = (const unsigned*)&w3;
                const unsigned* u4 = (const unsigned*)&w4;
                #pragma unroll
                for (int q = 0; q < 4; q++) {
                    ah += blo(u1[q]) * hb[2*q] + bhi(u1[q]) * hb[2*q+1];
                    ah += blo(u2[q]) * gh[2*q] + bhi(u2[q]) * gh[2*q+1];
                    ac += blo(u3[q]) * cb[2*q] + bhi(u3[q]) * cb[2*q+1];
                    ac += blo(u4[q]) * gc[2*q] + bhi(u4[q]) * gc[2*q+1];
                }
            }
            float hnv = sig_(ah), cnv = sig_(ac);
            HNs[r * 64 + c] = hnv;
            CNs[r * 64 + c] = cnv;
            size_t o = (size_t)(brow + r) * (T_ * H_) + (size_t)t * H_ + c;
            oh[o] = hnv;
            oc[o] = cnv;
        }

        if (t + 1 == T_) break;
        __syncthreads();

        // ---- epilogue B: X_{t+1} (premultiplied) -> XBf ----
        float* XBf = part;
        {
            const int j = tid & 127;
            const int r = tid >> 7;
            const int jj = j & 63;
            const float* S = (j < 64) ? HNs : CNs;
            float bias = (j < 64) ? BL[128 + jj] : BL[192 + jj];
            float a0 = bias;
            const int swz = j & 7;
            #pragma unroll
            for (int kk = 0; kk < 8; kk++) {
                const int pc = ((kk ^ swz) << 3);
                uint4 w = *(const uint4*)&WL[W_G + j * 64 + pc];
                const unsigned* u = (const unsigned*)&w;
                const float* s0 = &S[r * 64 + kk * 8];
                #pragma unroll
                for (int q = 0; q < 4; q++)
                    a0 += blo(u[q]) * s0[2*q] + bhi(u[q]) * s0[2*q+1];
            }
            XBf[j * 9 + r] = a0;
        }
        __syncthreads();

        // ---- store X_{t+1}^T: i8, 8B agent-scope stores (8 rows per col) ----
        if (tid < 128) {
            const float* Xb = &XBf[tid * 9];
            unsigned long long v = 0;
            #pragma unroll
            for (int r = 0; r < 8; r++)
                v |= ((unsigned long long)(unsigned char)q8_(Xb[r], SX_)) << (8 * r);
            __hip_atomic_store((unsigned long long*)(Xn + (size_t)tid * N_ + brow),
                               v, __ATOMIC_RELAXED, __HIP_MEMORY_SCOPE_AGENT);
        }
        __syncthreads();   // drains X stores (vmcnt 0 before s_barrier)

        // ---- arrive (2-level tree), then hide latency under epilogue C ----
        if (tid == 0) {
            unsigned old = __hip_atomic_fetch_add(grpc, 1u, __ATOMIC_RELAXED,
                                                  __HIP_MEMORY_SCOPE_AGENT);
            if (old == 16u * (unsigned)(t + 1) - 1u)   // last of group this step
                __hip_atomic_fetch_add(root, 1u, __ATOMIC_RELAXED,
                                       __HIP_MEMORY_SCOPE_AGENT);
        }

        // ---- epilogue C: h_lstm/c_lstm for t+1 -> HLs/CLs ----
        if (tid < 512) {
            const int c = tid & 63;
            const int r = tid >> 6;
            float z[4];
            #pragma unroll
            for (int g = 0; g < 4; g++) z[g] = BL[256 + g * 64 + c];
            const int swz1 = c & 1, swz = c & 7;
            #pragma unroll
            for (int g = 0; g < 4; g++) {
                const ushort_t* Krow = Wblob + W_K + (g * 64 + c) * 16;  // GLOBAL (L2-hot)
                #pragma unroll
                for (int dd = 0; dd < 2; dd++) {
                    const int pc = ((dd ^ swz1) << 3);
                    uint4 w = *(const uint4*)&Krow[pc];
                    const unsigned* u = (const unsigned*)&w;
                    const float* xb = &XSs[r * 16 + dd * 8];
                    #pragma unroll
                    for (int q = 0; q < 4; q++)
                        z[g] += blo(u[q]) * xb[2*q] + bhi(u[q]) * xb[2*q+1];
                }
                const ushort_t* Rrow = &WL[W_R + (g * 64 + c) * 64];
                #pragma unroll
                for (int kk = 0; kk < 8; kk++) {
                    const int pc = ((kk ^ swz) << 3);
                    uint4 w = *(const uint4*)&Rrow[pc];
                    const unsigned* u = (const unsigned*)&w;
                    const float* hb = &HNs[r * 64 + kk * 8];
                    #pragma unroll
                    for (int q = 0; q < 4; q++)
                        z[g] += blo(u[q]) * hb[2*q] + bhi(u[q]) * hb[2*q+1];
                }
            }
            float clv = sig_(z[1]) * CNs[r * 64 + c] + sig_(z[0]) * tanh_(z[2]);
            float hlv = sig_(z[3]) * tanh_(clv);
            CLs[r * 64 + c] = clv;
            HLs[r * 64 + c] = hlv;
        }

        // ---- poll root ----
        if (tid == 0) {
            const unsigned target = 16u * (unsigned)(t + 1);
            while (__hip_atomic_load(root, __ATOMIC_RELAXED, __HIP_MEMORY_SCOPE_AGENT) < target)
                __builtin_amdgcn_s_sleep(1);
        }
        __syncthreads();
        asm volatile("" ::: "memory");
    }
}

extern "C" void kernel_launch(void* const* d_in, const int* in_sizes, int n_in,
                              void* d_out, int out_size, void* d_ws, size_t ws_size,
                              hipStream_t stream) {
    const float* xin = (const float*)d_in[0];
    const float* h0  = (const float*)d_in[1];
    const float* c0  = (const float*)d_in[2];
    const float* A   = (const float*)d_in[3];
    const float* Wgh = (const float*)d_in[4];
    const float* bgh = (const float*)d_in[5];
    const float* Wgc = (const float*)d_in[6];
    const float* bgc = (const float*)d_in[7];
    const float* Whc = (const float*)d_in[8];
    const float* Whp = (const float*)d_in[9];
    const float* bh  = (const float*)d_in[10];
    const float* Wcc = (const float*)d_in[11];
    const float* Wcp = (const float*)d_in[12];
    const float* bc  = (const float*)d_in[13];
    const float* K   = (const float*)d_in[14];
    const float* R   = (const float*)d_in[15];
    const float* bl  = (const float*)d_in[16];

    const size_t fixed = (size_t)N_ * N_            // A i8
                       + (size_t)N_ * H_ * 4 * 2
                       + BLOB_BYTES + 4096;
    const bool deep = ws_size >= fixed + (size_t)(T_ + 1) * SLOT_BYTES;
    const int nslots = deep ? (T_ + 1) : 2;

    char* w = (char*)d_ws;
    i8_t* Ab8      = (i8_t*)w;      w += (size_t)N_ * N_;
    i8_t* Xs       = (i8_t*)w;      w += (size_t)nslots * SLOT_BYTES;
    float* hl      = (float*)w;     w += (size_t)N_ * H_ * 4;
    float* cl      = (float*)w;     w += (size_t)N_ * H_ * 4;
    ushort_t* blob = (ushort_t*)w;  w += BLOB_BYTES;
    unsigned* cnt  = (unsigned*)w;  w += 4096;

    float* oh = (float*)d_out;
    float* oc = oh + (size_t)N_ * T_ * H_;

    convert_A_kernel<<<(N_ * N_) / (256 * 4), 256, 0, stream>>>(A, Ab8, cnt);
    convert_W_kernel<<<16, 256, 0, stream>>>(Whc, Whp, Wcc, Wcp, Wgh, Wgc, R, K,
                                             bh, bc, bgh, bgc, bl, blob);
    prologue_kernel<<<N_, 64, 0, stream>>>(xin, h0, c0, Wgh, bgh, Wgc, bgc,
                                           K, R, bl, Xs, hl, cl);

    void* args[] = { (void*)&Ab8, (void*)&Xs, (void*)&hl, (void*)&cl,
                     (void*)&xin, (void*)&blob, (void*)&oh, (void*)&oc, (void*)&cnt };
    if (deep)
        hipLaunchCooperativeKernel((const void*)persistent_kernel<true>,
                                   dim3(NBLK), dim3(NTHR), args, 0, stream);
    else
        hipLaunchCooperativeKernel((const void*)persistent_kernel<false>,
                                   dim3(NBLK), dim3(NTHR), args, 0, stream);
}